// Round 4
// baseline (310.716 us; speedup 1.0000x reference)
//
#include <hip/hip_runtime.h>

// 3x3 conv (sparse weights treated dense), NCHW/OIHW, stride1 pad1, fp32 I/O.
// B=32, CIN=COUT=256, H=W=56.
//
// R4: implicit-GEMM, mfma_f32_16x16x32_bf16.
//  conv_mfma: block = 256 cout x 112 pix (2 output rows), 4 waves ALL in M
//  (wave = 64 couts, acc[4][7]) -> each 1KB B-frag LDS read feeds 4 MFMAs,
//  halving LDS traffic vs R2/R3. Weights global->VGPR (4 frags/tap, unrolled,
//  compiler-pipelined). x staged via global_load_lds dwordx4, double-buffered,
//  counted vmcnt(5) so next tile's loads fly across barriers (T3/T4).

typedef __attribute__((ext_vector_type(8))) short short8;
typedef __attribute__((ext_vector_type(4))) float f32x4;
typedef __attribute__((ext_vector_type(4))) int i32x4;

constexpr int BB = 32, CIN = 256, COUT = 256, H = 56, W = 56, HW = H * W;
constexpr int HP = 58, WP = 58;

constexpr size_t XP_ELEMS = (size_t)BB * HP * WP * CIN;
constexpr size_t WB_ELEMS = (size_t)COUT * 9 * CIN;
constexpr size_t WS_NEEDED = (XP_ELEMS + WB_ELEMS) * 2;

__device__ __forceinline__ ushort f2bf(float f) {
    unsigned x = __float_as_uint(f);
    unsigned r = (x + 0x7FFFu + ((x >> 16) & 1u)) >> 16;   // RNE
    return (ushort)r;
}

// ---------------- prep kernels (unchanged from R3) ----------------

__global__ __launch_bounds__(256)
void prep_xp(const float* __restrict__ x, ushort* __restrict__ xp) {
    const int bi = blockIdx.x;            // b*58 + padded row i
    const int b = bi / HP, i = bi % HP;
    ushort* dst = xp + (size_t)bi * WP * CIN;
    const int tid = threadIdx.x;

    if (i == 0 || i == HP - 1) {
        i32x4 z = {0, 0, 0, 0};
        for (int k = tid; k < WP * CIN / 8; k += 256) ((i32x4*)dst)[k] = z;
        return;
    }

    __shared__ ushort t[W][CIN + 2];
    const int lane = tid & 63, wv = tid >> 6;
    if (lane < W) {
        const float* src = x + (size_t)b * CIN * HW + (size_t)(i - 1) * W + lane;
        for (int cin = wv; cin < CIN; cin += 4)
            t[lane][cin] = f2bf(src[(size_t)cin * HW]);
    }
    __syncthreads();
    for (int c = 0; c < WP; ++c)
        dst[c * CIN + tid] = (c == 0 || c == WP - 1) ? (ushort)0 : t[c - 1][tid];
}

__global__ __launch_bounds__(256)
void prep_wb(const float* __restrict__ w, ushort* __restrict__ wb) {
    const int d = blockIdx.x * 256 + threadIdx.x;  // (cout*9+tap)*256+cin
    const int cin = d & 255;
    const int rest = d >> 8;
    const int tap = rest % 9;
    const int cout = rest / 9;
    wb[d] = f2bf(w[((size_t)cout * CIN + cin) * 9 + tap]);
}

// ---------------- MFMA conv ----------------

#define SCHED_FENCE() __builtin_amdgcn_sched_barrier(0)

__device__ __forceinline__ void gload_lds16(const ushort* g, ushort* l) {
    __builtin_amdgcn_global_load_lds(
        (const __attribute__((address_space(1))) void*)g,
        (__attribute__((address_space(3))) void*)l, 16, 0, 0);
}

// xs buffer: 1280 chunks of 16B per buffer. chunk c = slot*5 + piece;
// slot = r*58 + col (4 input rows x 58 cols = 232 slots), pieces 0..3 hold
// 8 cins each (64B data), piece 4 is pad (dummy-loaded). Byte addr of
// (slot, kgroup g) = slot*80 + g*16  -> bank base (20*slot+4g)%32, uniform.
constexpr int XCHUNKS = 1280;            // 232*5 = 1160 used, rest pad

__global__ __launch_bounds__(256, 3)
void conv_mfma(const ushort* __restrict__ xp, const ushort* __restrict__ wb,
               float* __restrict__ out) {
    // XCD-aware swizzle: 896 blocks = 8 * 112
    int bx = blockIdx.x;
    bx = (bx & 7) * 112 + (bx >> 3);

    const int b  = bx / 28;
    const int h0 = (bx % 28) * 2;          // first output row (= first padded in-row)

    const int tid  = threadIdx.x;
    const int wv   = tid >> 6;             // wave -> couts [64wv, 64wv+64)
    const int lane = tid & 63;
    const int ml   = lane & 15;
    const int g    = lane >> 4;

    __shared__ ushort xs[2][XCHUNKS * 8];  // 2 x 20480 B

    // B-frag LDS elem offsets: pixel p = nf*16+ml -> slot = hl*58+wl
    int boff[7];
    #pragma unroll
    for (int nf = 0; nf < 7; ++nf) {
        const int p = nf * 16 + ml;
        const int hl = (p >= 56) ? 1 : 0;
        const int wl = p - 56 * hl;
        boff[nf] = (hl * 58 + wl) * 40 + 8 * g;
    }

    // gload src elem offsets (5 chunks per thread per cin-block)
    const size_t base_b = ((size_t)b * HP + h0) * WP * CIN;
    int goff[5];
    #pragma unroll
    for (int k = 0; k < 5; ++k) {
        const int c = 256 * k + 64 * wv + lane;
        const int s = c / 5, piece = c - s * 5;
        const bool ok = (c < 1160) && (piece < 4);
        goff[k] = ok ? (s * 256 + piece * 8) : 0;     // slots contiguous in xp!
    }

    // A-frag global base: wave wv owns couts 64wv+16fm+ml; frag fm at +fm*36864
    const ushort* abase = wb + (size_t)((64 * wv + ml) * 9) * 256 + 8 * g;

    f32x4 acc[4][7] = {};

    // prologue: stage cb0 -> buf0
    #pragma unroll
    for (int k = 0; k < 5; ++k)
        gload_lds16(xp + base_b + goff[k], &xs[0][(256 * k + 64 * wv) * 8]);

    for (int cb = 0; cb < 8; ++cb) {
        const int cur = cb & 1;
        __builtin_amdgcn_s_barrier();      // B1: all waves done reading buf[cur^1]
        SCHED_FENCE();
        if (cb < 7) {
            #pragma unroll
            for (int k = 0; k < 5; ++k)
                gload_lds16(xp + base_b + goff[k] + (cb + 1) * 32,
                            &xs[cur ^ 1][(256 * k + 64 * wv) * 8]);
            SCHED_FENCE();
            asm volatile("s_waitcnt vmcnt(5)" ::: "memory");  // cb's 5 done, cb+1's fly
            SCHED_FENCE();
        } else {
            SCHED_FENCE();
            asm volatile("s_waitcnt vmcnt(0)" ::: "memory");
            SCHED_FENCE();
        }
        __builtin_amdgcn_s_barrier();      // B2: buf[cur] fully written (all waves)
        SCHED_FENCE();

        const ushort* xbuf = &xs[cur][0];
        const ushort* ab = abase + cb * 32;
        #pragma unroll
        for (int tap = 0; tap < 9; ++tap) {
            const int kh = tap / 3, kw = tap - kh * 3;
            const int toff = (kh * 58 + kw) * 40;

            short8 a0 = *(const short8*)(ab + tap * 256);
            short8 a1 = *(const short8*)(ab + tap * 256 + 36864);
            short8 a2 = *(const short8*)(ab + tap * 256 + 2 * 36864);
            short8 a3 = *(const short8*)(ab + tap * 256 + 3 * 36864);
            #pragma unroll
            for (int nf = 0; nf < 7; ++nf) {
                const short8 bf = *(const short8*)(xbuf + boff[nf] + toff);
                acc[0][nf] = __builtin_amdgcn_mfma_f32_16x16x32_bf16(a0, bf, acc[0][nf], 0, 0, 0);
                acc[1][nf] = __builtin_amdgcn_mfma_f32_16x16x32_bf16(a1, bf, acc[1][nf], 0, 0, 0);
                acc[2][nf] = __builtin_amdgcn_mfma_f32_16x16x32_bf16(a2, bf, acc[2][nf], 0, 0, 0);
                acc[3][nf] = __builtin_amdgcn_mfma_f32_16x16x32_bf16(a3, bf, acc[3][nf], 0, 0, 0);
            }
        }
    }

    // epilogue: D[row=4g+r][col=ml] (verified R2/R3)
    float* ob = out + (size_t)b * COUT * HW + (size_t)h0 * W;
    #pragma unroll
    for (int fm = 0; fm < 4; ++fm)
        #pragma unroll
        for (int nf = 0; nf < 7; ++nf)
            #pragma unroll
            for (int r = 0; r < 4; ++r) {
                const int cout_l = 64 * wv + 16 * fm + 4 * g + r;
                const int p = nf * 16 + ml;
                const int hh = (p >= 56) ? 1 : 0;
                const int ww = p - 56 * hh;
                ob[(size_t)cout_l * HW + hh * W + ww] = acc[fm][nf][r];
            }
}

// ---------------- R1 fallback (fp32 sparse direct) ----------------

constexpr int WSZ = CIN * 9;
constexpr int NIN = 54 * 54;

__global__ __launch_bounds__(256)
void sparse_conv3x3(const float* __restrict__ x,
                    const float* __restrict__ wgt,
                    float* __restrict__ out) {
    const int bc = blockIdx.x, cout = bc % COUT, b = bc / COUT;
    const int tid = threadIdx.x;
    __shared__ int2 s_ent[WSZ];
    __shared__ unsigned char s_kk[WSZ];
    __shared__ int s_cnt[257];
    const float* wc = wgt + (size_t)cout * WSZ;
    float mv[9]; int cnt = 0;
    #pragma unroll
    for (int i = 0; i < 9; ++i) { mv[i] = wc[tid * 9 + i]; if (mv[i] != 0.0f) cnt++; }
    s_cnt[tid] = cnt; __syncthreads();
    if (tid == 0) { int run = 0; for (int t = 0; t < 256; ++t) { int c = s_cnt[t]; s_cnt[t] = run; run += c; } s_cnt[256] = run; }
    __syncthreads();
    { int pos = s_cnt[tid];
      #pragma unroll
      for (int i = 0; i < 9; ++i) if (mv[i] != 0.0f) {
          const int kh = i / 3, kw = i - kh * 3;
          int2 e; e.x = (tid * HW + (kh - 1) * W + (kw - 1)) * 4; e.y = __float_as_int(mv[i]);
          s_ent[pos] = e; s_kk[pos] = (unsigned char)(kh | (kw << 4)); pos++; } }
    __syncthreads();
    const int nnz = s_cnt[256];
    const char* xb = (const char*)(x + (size_t)b * CIN * HW);
    float* ob = out + (size_t)bc * HW;
    for (int o = tid; o < HW; o += 256) {
        int h, w; bool interior = (o < NIN);
        if (interior) { h = 1 + o / 54; w = 1 + (o - (h - 1) * 54); }
        else { int o2 = o - NIN;
            if (o2 < 56) { h = 0; w = o2; } else if (o2 < 112) { h = 55; w = o2 - 56; }
            else if (o2 < 166) { h = 1 + (o2 - 112); w = 0; } else { h = 1 + (o2 - 166); w = 55; } }
        const char* pb = xb + (size_t)(h * W + w) * 4;
        float acc = 0.0f;
        if (interior) {
            #pragma unroll 4
            for (int e = 0; e < nnz; ++e) { const int2 en = s_ent[e];
                acc = fmaf(__int_as_float(en.y), *(const float*)(pb + en.x), acc); }
        } else {
            const int h1 = h - 1, w1 = w - 1;
            for (int e = 0; e < nnz; ++e) { const int2 en = s_ent[e]; const int kk = s_kk[e];
                const int hh = h1 + (kk & 15), ww = w1 + (kk >> 4);
                if ((unsigned)hh < (unsigned)H && (unsigned)ww < (unsigned)W)
                    acc = fmaf(__int_as_float(en.y), *(const float*)(pb + en.x), acc); } }
        ob[h * W + w] = acc;
    }
}

// ---------------- launch ----------------

extern "C" void kernel_launch(void* const* d_in, const int* in_sizes, int n_in,
                              void* d_out, int out_size, void* d_ws, size_t ws_size,
                              hipStream_t stream) {
    const float* x = (const float*)d_in[0];
    const float* w = (const float*)d_in[1];
    float* out = (float*)d_out;

    if (ws_size >= WS_NEEDED) {
        ushort* xp = (ushort*)d_ws;
        ushort* wbp = xp + XP_ELEMS;
        prep_xp<<<BB * HP, 256, 0, stream>>>(x, xp);
        prep_wb<<<(int)(WB_ELEMS / 256), 256, 0, stream>>>(w, wbp);
        conv_mfma<<<896, 256, 0, stream>>>(xp, wbp, out);
    } else {
        sparse_conv3x3<<<BB * COUT, 256, 0, stream>>>(x, w, out);
    }
}

// Round 5
// 188.824 us; speedup vs baseline: 1.6455x; 1.6455x over previous
//
#include <hip/hip_runtime.h>

// 3x3 conv (sparse weights treated dense), NCHW/OIHW, stride1 pad1, fp32 I/O.
// B=32, CIN=COUT=256, H=W=56.
//
// R5: identical to R4 except __launch_bounds__(256, 2) on conv_mfma.
//  R4's (256,3) capped unified VGPR/AGPR at ~170 < the ~200 needed
//  (acc[4][7] = 112 + pipeline temps) -> accumulator spill to scratch:
//  VGPR_Count=84, WRITE 476MB, FETCH 250MB, MfmaUtil 16%. (256,2) caps at
//  256 regs -> no spill, same effective occupancy (2 blocks/CU).

typedef __attribute__((ext_vector_type(8))) short short8;
typedef __attribute__((ext_vector_type(4))) float f32x4;
typedef __attribute__((ext_vector_type(4))) int i32x4;

constexpr int BB = 32, CIN = 256, COUT = 256, H = 56, W = 56, HW = H * W;
constexpr int HP = 58, WP = 58;

constexpr size_t XP_ELEMS = (size_t)BB * HP * WP * CIN;
constexpr size_t WB_ELEMS = (size_t)COUT * 9 * CIN;
constexpr size_t WS_NEEDED = (XP_ELEMS + WB_ELEMS) * 2;

__device__ __forceinline__ ushort f2bf(float f) {
    unsigned x = __float_as_uint(f);
    unsigned r = (x + 0x7FFFu + ((x >> 16) & 1u)) >> 16;   // RNE
    return (ushort)r;
}

// ---------------- prep kernels ----------------

__global__ __launch_bounds__(256)
void prep_xp(const float* __restrict__ x, ushort* __restrict__ xp) {
    const int bi = blockIdx.x;            // b*58 + padded row i
    const int b = bi / HP, i = bi % HP;
    ushort* dst = xp + (size_t)bi * WP * CIN;
    const int tid = threadIdx.x;

    if (i == 0 || i == HP - 1) {
        i32x4 z = {0, 0, 0, 0};
        for (int k = tid; k < WP * CIN / 8; k += 256) ((i32x4*)dst)[k] = z;
        return;
    }

    __shared__ ushort t[W][CIN + 2];
    const int lane = tid & 63, wv = tid >> 6;
    if (lane < W) {
        const float* src = x + (size_t)b * CIN * HW + (size_t)(i - 1) * W + lane;
        for (int cin = wv; cin < CIN; cin += 4)
            t[lane][cin] = f2bf(src[(size_t)cin * HW]);
    }
    __syncthreads();
    for (int c = 0; c < WP; ++c)
        dst[c * CIN + tid] = (c == 0 || c == WP - 1) ? (ushort)0 : t[c - 1][tid];
}

__global__ __launch_bounds__(256)
void prep_wb(const float* __restrict__ w, ushort* __restrict__ wb) {
    const int d = blockIdx.x * 256 + threadIdx.x;  // (cout*9+tap)*256+cin
    const int cin = d & 255;
    const int rest = d >> 8;
    const int tap = rest % 9;
    const int cout = rest / 9;
    wb[d] = f2bf(w[((size_t)cout * CIN + cin) * 9 + tap]);
}

// ---------------- MFMA conv ----------------

#define SCHED_FENCE() __builtin_amdgcn_sched_barrier(0)

__device__ __forceinline__ void gload_lds16(const ushort* g, ushort* l) {
    __builtin_amdgcn_global_load_lds(
        (const __attribute__((address_space(1))) void*)g,
        (__attribute__((address_space(3))) void*)l, 16, 0, 0);
}

// xs buffer: chunk c = slot*5 + piece; slot = r*58 + col (4 rows x 58 cols),
// pieces 0..3 = 8 cins each (64B), piece 4 = pad (dummy-loaded).
constexpr int XCHUNKS = 1280;            // 232*5 = 1160 used, rest pad

__global__ __launch_bounds__(256, 2)
void conv_mfma(const ushort* __restrict__ xp, const ushort* __restrict__ wb,
               float* __restrict__ out) {
    // XCD-aware swizzle: 896 blocks = 8 * 112
    int bx = blockIdx.x;
    bx = (bx & 7) * 112 + (bx >> 3);

    const int b  = bx / 28;
    const int h0 = (bx % 28) * 2;

    const int tid  = threadIdx.x;
    const int wv   = tid >> 6;             // wave -> couts [64wv, 64wv+64)
    const int lane = tid & 63;
    const int ml   = lane & 15;
    const int g    = lane >> 4;

    __shared__ ushort xs[2][XCHUNKS * 8];  // 2 x 20480 B

    // B-frag LDS elem offsets: pixel p = nf*16+ml -> slot = hl*58+wl
    int boff[7];
    #pragma unroll
    for (int nf = 0; nf < 7; ++nf) {
        const int p = nf * 16 + ml;
        const int hl = (p >= 56) ? 1 : 0;
        const int wl = p - 56 * hl;
        boff[nf] = (hl * 58 + wl) * 40 + 8 * g;
    }

    // gload src elem offsets (5 chunks per thread per cin-block)
    const size_t base_b = ((size_t)b * HP + h0) * WP * CIN;
    int goff[5];
    #pragma unroll
    for (int k = 0; k < 5; ++k) {
        const int c = 256 * k + 64 * wv + lane;
        const int s = c / 5, piece = c - s * 5;
        const bool ok = (c < 1160) && (piece < 4);
        goff[k] = ok ? (s * 256 + piece * 8) : 0;     // slots contiguous in xp
    }

    // A-frag global base: wave wv covers couts {64wv+16fm+ml}, frag fm at +fm*36864
    const ushort* abase = wb + (size_t)((64 * wv + ml) * 9) * 256 + 8 * g;

    f32x4 acc[4][7] = {};

    // prologue: stage cb0 -> buf0
    #pragma unroll
    for (int k = 0; k < 5; ++k)
        gload_lds16(xp + base_b + goff[k], &xs[0][(256 * k + 64 * wv) * 8]);

    for (int cb = 0; cb < 8; ++cb) {
        const int cur = cb & 1;
        __builtin_amdgcn_s_barrier();      // B1: all waves done reading buf[cur^1]
        SCHED_FENCE();
        if (cb < 7) {
            #pragma unroll
            for (int k = 0; k < 5; ++k)
                gload_lds16(xp + base_b + goff[k] + (cb + 1) * 32,
                            &xs[cur ^ 1][(256 * k + 64 * wv) * 8]);
            SCHED_FENCE();
            asm volatile("s_waitcnt vmcnt(5)" ::: "memory");  // cb's 5 done, cb+1's fly
            SCHED_FENCE();
        } else {
            SCHED_FENCE();
            asm volatile("s_waitcnt vmcnt(0)" ::: "memory");
            SCHED_FENCE();
        }
        __builtin_amdgcn_s_barrier();      // B2: buf[cur] fully written
        SCHED_FENCE();

        const ushort* xbuf = &xs[cur][0];
        const ushort* ab = abase + cb * 32;
        #pragma unroll
        for (int tap = 0; tap < 9; ++tap) {
            const int kh = tap / 3, kw = tap - kh * 3;
            const int toff = (kh * 58 + kw) * 40;

            short8 a0 = *(const short8*)(ab + tap * 256);
            short8 a1 = *(const short8*)(ab + tap * 256 + 36864);
            short8 a2 = *(const short8*)(ab + tap * 256 + 2 * 36864);
            short8 a3 = *(const short8*)(ab + tap * 256 + 3 * 36864);
            #pragma unroll
            for (int nf = 0; nf < 7; ++nf) {
                const short8 bf = *(const short8*)(xbuf + boff[nf] + toff);
                acc[0][nf] = __builtin_amdgcn_mfma_f32_16x16x32_bf16(a0, bf, acc[0][nf], 0, 0, 0);
                acc[1][nf] = __builtin_amdgcn_mfma_f32_16x16x32_bf16(a1, bf, acc[1][nf], 0, 0, 0);
                acc[2][nf] = __builtin_amdgcn_mfma_f32_16x16x32_bf16(a2, bf, acc[2][nf], 0, 0, 0);
                acc[3][nf] = __builtin_amdgcn_mfma_f32_16x16x32_bf16(a3, bf, acc[3][nf], 0, 0, 0);
            }
        }
    }

    // epilogue: D[row=4g+r][col=ml] (verified R2-R4)
    float* ob = out + (size_t)b * COUT * HW + (size_t)h0 * W;
    #pragma unroll
    for (int fm = 0; fm < 4; ++fm)
        #pragma unroll
        for (int nf = 0; nf < 7; ++nf)
            #pragma unroll
            for (int r = 0; r < 4; ++r) {
                const int cout_l = 64 * wv + 16 * fm + 4 * g + r;
                const int p = nf * 16 + ml;
                const int hh = (p >= 56) ? 1 : 0;
                const int ww = p - 56 * hh;
                ob[(size_t)cout_l * HW + hh * W + ww] = acc[fm][nf][r];
            }
}

// ---------------- R1 fallback (fp32 sparse direct) ----------------

constexpr int WSZ = CIN * 9;
constexpr int NIN = 54 * 54;

__global__ __launch_bounds__(256)
void sparse_conv3x3(const float* __restrict__ x,
                    const float* __restrict__ wgt,
                    float* __restrict__ out) {
    const int bc = blockIdx.x, cout = bc % COUT, b = bc / COUT;
    const int tid = threadIdx.x;
    __shared__ int2 s_ent[WSZ];
    __shared__ unsigned char s_kk[WSZ];
    __shared__ int s_cnt[257];
    const float* wc = wgt + (size_t)cout * WSZ;
    float mv[9]; int cnt = 0;
    #pragma unroll
    for (int i = 0; i < 9; ++i) { mv[i] = wc[tid * 9 + i]; if (mv[i] != 0.0f) cnt++; }
    s_cnt[tid] = cnt; __syncthreads();
    if (tid == 0) { int run = 0; for (int t = 0; t < 256; ++t) { int c = s_cnt[t]; s_cnt[t] = run; run += c; } s_cnt[256] = run; }
    __syncthreads();
    { int pos = s_cnt[tid];
      #pragma unroll
      for (int i = 0; i < 9; ++i) if (mv[i] != 0.0f) {
          const int kh = i / 3, kw = i - kh * 3;
          int2 e; e.x = (tid * HW + (kh - 1) * W + (kw - 1)) * 4; e.y = __float_as_int(mv[i]);
          s_ent[pos] = e; s_kk[pos] = (unsigned char)(kh | (kw << 4)); pos++; } }
    __syncthreads();
    const int nnz = s_cnt[256];
    const char* xb = (const char*)(x + (size_t)b * CIN * HW);
    float* ob = out + (size_t)bc * HW;
    for (int o = tid; o < HW; o += 256) {
        int h, w; bool interior = (o < NIN);
        if (interior) { h = 1 + o / 54; w = 1 + (o - (h - 1) * 54); }
        else { int o2 = o - NIN;
            if (o2 < 56) { h = 0; w = o2; } else if (o2 < 112) { h = 55; w = o2 - 56; }
            else if (o2 < 166) { h = 1 + (o2 - 112); w = 0; } else { h = 1 + (o2 - 166); w = 55; } }
        const char* pb = xb + (size_t)(h * W + w) * 4;
        float acc = 0.0f;
        if (interior) {
            #pragma unroll 4
            for (int e = 0; e < nnz; ++e) { const int2 en = s_ent[e];
                acc = fmaf(__int_as_float(en.y), *(const float*)(pb + en.x), acc); }
        } else {
            const int h1 = h - 1, w1 = w - 1;
            for (int e = 0; e < nnz; ++e) { const int2 en = s_ent[e]; const int kk = s_kk[e];
                const int hh = h1 + (kk & 15), ww = w1 + (kk >> 4);
                if ((unsigned)hh < (unsigned)H && (unsigned)ww < (unsigned)W)
                    acc = fmaf(__int_as_float(en.y), *(const float*)(pb + en.x), acc); } }
        ob[h * W + w] = acc;
    }
}

// ---------------- launch ----------------

extern "C" void kernel_launch(void* const* d_in, const int* in_sizes, int n_in,
                              void* d_out, int out_size, void* d_ws, size_t ws_size,
                              hipStream_t stream) {
    const float* x = (const float*)d_in[0];
    const float* w = (const float*)d_in[1];
    float* out = (float*)d_out;

    if (ws_size >= WS_NEEDED) {
        ushort* xp = (ushort*)d_ws;
        ushort* wbp = xp + XP_ELEMS;
        prep_xp<<<BB * HP, 256, 0, stream>>>(x, xp);
        prep_wb<<<(int)(WB_ELEMS / 256), 256, 0, stream>>>(w, wbp);
        conv_mfma<<<896, 256, 0, stream>>>(xp, wbp, out);
    } else {
        sparse_conv3x3<<<BB * COUT, 256, 0, stream>>>(x, w, out);
    }
}